// Round 1
// baseline (7498.396 us; speedup 1.0000x reference)
//
#include <hip/hip_runtime.h>
#include <math.h>

#define NTH 256

__device__ __forceinline__ float fast_sigmoid(float x) { return 1.0f / (1.0f + __expf(-x)); }
__device__ __forceinline__ float fast_tanh(float x)    { return 1.0f - 2.0f / (__expf(2.0f * x) + 1.0f); }

// LDS layout (floats):
//  [0,4320)      : four generic 1080-float buffers B0..B3
//  [4320,4644)   : wq2,wk2,wv2,wo2 (81 each)
//  [4644,4671)   : bo2, ln2g, ln2b (9 each)
//  [4671,4788)   : kv(81), ksum(9), qk(9), mu9(9), rs9(9)
//  [4788,4800)   : revin stats (mu, rinv)
//  [4800,5160)   : bo4, ln4g, ln4b (120 each)
//  [5160,5480)   : w_ih(128), b_ih+b_hh(128), cg_w(32), cg_ub(32)
//  [5480,10088)  : w_hh padded rows 128 x 36 (16B aligned rows)
//  [10088,11240) : cg_uw padded rows 32 x 36
// Phase C aliases: gates=sm[0..864), gc=sm[1152..1440), h=sm[3240..3528), c=sm[3528..3816)
// Phase D aliases: t1=sm[0..540), tflat=sm[540..675)

extern "C" __global__ void __launch_bounds__(NTH)
se_kernel(const float* __restrict__ x,
          const float* __restrict__ bn_g, const float* __restrict__ bn_b,
          const float* __restrict__ bn_m, const float* __restrict__ bn_v,
          const float* __restrict__ wq2, const float* __restrict__ wk2,
          const float* __restrict__ wv2, const float* __restrict__ wo2,
          const float* __restrict__ bo2, const float* __restrict__ ln2g,
          const float* __restrict__ ln2b,
          const float* __restrict__ wq4, const float* __restrict__ wk4,
          const float* __restrict__ wv4, const float* __restrict__ wo4,
          const float* __restrict__ bo4, const float* __restrict__ ln4g,
          const float* __restrict__ ln4b,
          const float* __restrict__ w_ih, const float* __restrict__ w_hh,
          const float* __restrict__ b_ih, const float* __restrict__ b_hh,
          const float* __restrict__ cg_w, const float* __restrict__ cg_uw,
          const float* __restrict__ cg_ub,
          const float* __restrict__ w6, const float* __restrict__ b6,
          const float* __restrict__ w7, const float* __restrict__ b7,
          const float* __restrict__ rev_w, const float* __restrict__ rev_b,
          float* __restrict__ out, int Bn)
{
    __shared__ __align__(16) float sm[11240];
    const int tid = threadIdx.x;
    const int b   = blockIdx.x;

    float* B0 = sm;
    float* B1 = sm + 1080;
    float* B2 = sm + 2160;
    float* B3 = sm + 3240;
    float* sWQ2 = sm + 4320; float* sWK2 = sm + 4401;
    float* sWV2 = sm + 4482; float* sWO2 = sm + 4563;
    float* sBO2 = sm + 4644; float* sLN2G = sm + 4653; float* sLN2B = sm + 4662;
    float* sKV = sm + 4671; float* sKS = sm + 4752; float* sQK = sm + 4761;
    float* sMU9 = sm + 4770; float* sRS9 = sm + 4779;
    float* sST  = sm + 4788;
    float* sBO4 = sm + 4800; float* sLN4G = sm + 4920; float* sLN4B = sm + 5040;
    float* sWIH = sm + 5160; float* sBB = sm + 5288;
    float* sCGW = sm + 5416; float* sCGUB = sm + 5448;
    float* sWHH = sm + 5480;    // 128 rows, stride 36
    float* sCGUW = sm + 10088;  // 32 rows, stride 36
    float* sGATES = sm;         // [v][96] i/f/g only (o-gate is dead)
    float* sGC = sm + 1152;     // 288
    float* sH = sm + 3240;      // 288
    float* sC = sm + 3528;      // 288
    float* sT1 = sm;            // 540
    float* sTF = sm + 540;      // 135

    // ---- Phase 0: BatchNorm (eval) + stage all weights to LDS ----
    for (int i = tid; i < 1080; i += NTH) {
        float xv = x[(size_t)b * 1080 + i];
        B0[i] = (xv - bn_m[i]) * rsqrtf(bn_v[i] + 1e-5f) * bn_g[i] + bn_b[i];
    }
    for (int i = tid; i < 81; i += NTH) {
        sWQ2[i] = wq2[i]; sWK2[i] = wk2[i]; sWV2[i] = wv2[i]; sWO2[i] = wo2[i];
    }
    if (tid < 9) { sBO2[tid] = bo2[tid]; sLN2G[tid] = ln2g[tid]; sLN2B[tid] = ln2b[tid]; }
    for (int i = tid; i < 120; i += NTH) { sBO4[i] = bo4[i]; sLN4G[i] = ln4g[i]; sLN4B[i] = ln4b[i]; }
    for (int i = tid; i < 128; i += NTH) { sWIH[i] = w_ih[i]; sBB[i] = b_ih[i] + b_hh[i]; }
    if (tid < 32) { sCGW[tid] = cg_w[tid]; sCGUB[tid] = cg_ub[tid]; }
    for (int i = tid; i < 4096; i += NTH) sWHH[(i >> 5) * 36 + (i & 31)] = w_hh[i];
    for (int i = tid; i < 1024; i += NTH) sCGUW[(i >> 5) * 36 + (i & 31)] = cg_uw[i];
    __syncthreads();

    // ---- Phase A: lin_attn_2 over [s=120, d=9] ----
    // A1: Q,K,V (phi = elu+1: z>=0 -> z+1, else exp(z))
    for (int idx = tid; idx < 1080; idx += NTH) {
        int s = idx / 9, e = idx - s * 9;
        float aq = 0.f, ak = 0.f, av = 0.f;
        #pragma unroll
        for (int d = 0; d < 9; ++d) {
            float xv = B0[s * 9 + d];
            aq = fmaf(xv, sWQ2[e * 9 + d], aq);
            ak = fmaf(xv, sWK2[e * 9 + d], ak);
            av = fmaf(xv, sWV2[e * 9 + d], av);
        }
        B1[idx] = aq >= 0.f ? aq + 1.f : __expf(aq);
        B2[idx] = ak >= 0.f ? ak + 1.f : __expf(ak);
        B3[idx] = av;
    }
    __syncthreads();
    // A2: kv[d][e] = sum_s K[s][d]*V[s][e]; ksum[d]
    if (tid < 81) {
        int d = tid / 9, e = tid - d * 9;
        float acc = 0.f;
        for (int s = 0; s < 120; ++s) acc = fmaf(B2[s * 9 + d], B3[s * 9 + e], acc);
        sKV[tid] = acc;
    } else if (tid < 90) {
        int d = tid - 81;
        float acc = 0.f;
        for (int s = 0; s < 120; ++s) acc += B2[s * 9 + d];
        sKS[d] = acc;
    }
    __syncthreads();
    // A3: o = (Q@kv) / max(Q.ksum, 1e-6)  -> B0
    for (int idx = tid; idx < 1080; idx += NTH) {
        int s = idx / 9, e = idx - s * 9;
        float num = 0.f, den = 0.f;
        #pragma unroll
        for (int d = 0; d < 9; ++d) {
            float qv = B1[s * 9 + d];
            num = fmaf(qv, sKV[d * 9 + e], num);
            den = fmaf(qv, sKS[d], den);
        }
        B0[idx] = num / fmaxf(den, 1e-6f);
    }
    __syncthreads();
    // A4: y = o@wo2^T + bo2 + o  -> B1
    for (int idx = tid; idx < 1080; idx += NTH) {
        int s = idx / 9, f = idx - s * 9;
        float acc = sBO2[f] + B0[s * 9 + f];
        #pragma unroll
        for (int e = 0; e < 9; ++e) acc = fmaf(B0[s * 9 + e], sWO2[f * 9 + e], acc);
        B1[idx] = acc;
    }
    __syncthreads();
    // A5: LayerNorm over 9 dims, then transpose -> B2[v][t] (u, attn4 input)
    if (tid < 120) {
        int s = tid;
        float sum = 0.f, sq = 0.f;
        #pragma unroll
        for (int f = 0; f < 9; ++f) { float v = B1[s * 9 + f]; sum += v; sq = fmaf(v, v, sq); }
        float mu = sum * (1.f / 9.f);
        float rs = rsqrtf(sq * (1.f / 9.f) - mu * mu + 1e-5f);
        #pragma unroll
        for (int f = 0; f < 9; ++f)
            B2[f * 120 + s] = (B1[s * 9 + f] - mu) * rs * sLN2G[f] + sLN2B[f];
    }
    __syncthreads();

    // ---- Phase B: lin_attn_4, S=1, dim 120, 9 sequences ----
    // B1: q4->B0, k4->B1, v4->B3. One thread per (matrix, weight-row e):
    // reads each weight row exactly once, accumulates all 9 variables.
    for (int idx = tid; idx < 360; idx += NTH) {
        int m = idx / 120, e = idx - m * 120;
        const float* W = (m == 0) ? wq4 : (m == 1) ? wk4 : wv4;
        const float* wr = &W[e * 120];
        float acc[9];
        #pragma unroll
        for (int v = 0; v < 9; ++v) acc[v] = 0.f;
        for (int d = 0; d < 120; ++d) {
            float wv = wr[d];
            #pragma unroll
            for (int v = 0; v < 9; ++v) acc[v] = fmaf(B2[v * 120 + d], wv, acc[v]);
        }
        if (m == 2) {
            #pragma unroll
            for (int v = 0; v < 9; ++v) B3[v * 120 + e] = acc[v];
        } else {
            float* dst = (m == 0) ? B0 : B1;
            #pragma unroll
            for (int v = 0; v < 9; ++v) {
                float a = acc[v];
                dst[v * 120 + e] = a >= 0.f ? a + 1.f : __expf(a);
            }
        }
    }
    __syncthreads();
    // B2: qk[v] = dot(q4,k4)
    if (tid < 9) {
        float acc = 0.f;
        for (int e = 0; e < 120; ++e) acc = fmaf(B0[tid * 120 + e], B1[tid * 120 + e], acc);
        sQK[tid] = acc;
    }
    __syncthreads();
    // B3: o4 = v4 * qk/max(qk,1e-6)  -> B0
    for (int idx = tid; idx < 1080; idx += NTH) {
        int v = idx / 120;
        float qk = sQK[v];
        B0[idx] = B3[idx] * (qk / fmaxf(qk, 1e-6f));
    }
    __syncthreads();
    // B4: y4 = o4@wo4^T + bo4 + o4 -> B1 (one thread per weight row)
    if (tid < 120) {
        int e = tid;
        const float* wr = &wo4[e * 120];
        float acc[9];
        #pragma unroll
        for (int v = 0; v < 9; ++v) acc[v] = 0.f;
        for (int f = 0; f < 120; ++f) {
            float wv = wr[f];
            #pragma unroll
            for (int v = 0; v < 9; ++v) acc[v] = fmaf(B0[v * 120 + f], wv, acc[v]);
        }
        #pragma unroll
        for (int v = 0; v < 9; ++v)
            B1[v * 120 + e] = acc[v] + sBO4[e] + B0[v * 120 + e];
    }
    __syncthreads();
    // B5a: LN stats per v over 120
    if (tid < 9) {
        float sum = 0.f, sq = 0.f;
        for (int e = 0; e < 120; ++e) { float v = B1[tid * 120 + e]; sum += v; sq = fmaf(v, v, sq); }
        float mu = sum * (1.f / 120.f);
        sMU9[tid] = mu;
        sRS9[tid] = rsqrtf(sq * (1.f / 120.f) - mu * mu + 1e-5f);
    }
    __syncthreads();
    // B5b: normalized -> B2[v][t]  (LSTM input sequence); init h,c = 0
    for (int idx = tid; idx < 1080; idx += NTH) {
        int v = idx / 120, e = idx - v * 120;
        B2[idx] = (B1[idx] - sMU9[v]) * sRS9[v] * sLN4G[e] + sLN4B[e];
    }
    for (int i = tid; i < 576; i += NTH) sH[i] = 0.f;  // h then c, contiguous
    __syncthreads();

    // ---- Phase C: CGLSTM, 120 steps, 9 sequences x hidden 32 ----
    // o-gate of the LSTM cell is never used (h_new = gc*tanh(c_new)) -> skip it.
    for (int t = 0; t < 120; ++t) {
        for (int idx = tid; idx < 1152; idx += NTH) {
            if (idx < 864) {  // i,f,g gates: [v][96]
                int v = idx / 96, j = idx - v * 96;
                float acc = fmaf(B2[v * 120 + t], sWIH[j], sBB[j]);
                const float4* w4 = (const float4*)&sWHH[j * 36];
                const float4* h4 = (const float4*)&sH[v * 32];
                #pragma unroll
                for (int q = 0; q < 8; ++q) {
                    float4 w = w4[q], h = h4[q];
                    acc = fmaf(w.x, h.x, acc); acc = fmaf(w.y, h.y, acc);
                    acc = fmaf(w.z, h.z, acc); acc = fmaf(w.w, h.w, acc);
                }
                sGATES[idx] = acc;
            } else {          // contextual gate pre-activation (uses OLD h)
                int r = idx - 864;
                int v = r >> 5, k = r & 31;
                float acc = fmaf(B2[v * 120 + t], sCGW[k], sCGUB[k]);
                const float4* w4 = (const float4*)&sCGUW[k * 36];
                const float4* h4 = (const float4*)&sH[v * 32];
                #pragma unroll
                for (int q = 0; q < 8; ++q) {
                    float4 w = w4[q], h = h4[q];
                    acc = fmaf(w.x, h.x, acc); acc = fmaf(w.y, h.y, acc);
                    acc = fmaf(w.z, h.z, acc); acc = fmaf(w.w, h.w, acc);
                }
                sGC[r] = acc;
            }
        }
        __syncthreads();
        for (int r = tid; r < 288; r += NTH) {
            int v = r >> 5, k = r & 31;
            int gb = v * 96 + k;
            float ig = fast_sigmoid(sGATES[gb]);
            float fg = fast_sigmoid(sGATES[gb + 32]);
            float gg = fast_tanh(sGATES[gb + 64]);
            float cn = fmaf(fg, sC[r], ig * gg);
            float gc = fast_sigmoid(sGC[r]);
            sC[r] = cn;
            sH[r] = gc * fast_tanh(cn);
        }
        __syncthreads();
    }

    // ---- Phase D: conv6(softplus) -> conv7(tanh) -> permute -> RevIN ----
    for (int idx = tid; idx < 540; idx += NTH) {
        int v = idx / 60, j = idx - v * 60;
        float acc = b6[j];
        const float* wr = &w6[j * 32];
        const float* hv = &sH[v * 32];
        #pragma unroll
        for (int k = 0; k < 32; ++k) acc = fmaf(hv[k], wr[k], acc);
        sT1[idx] = acc > 15.f ? acc : log1pf(__expf(acc));
    }
    __syncthreads();
    for (int idx = tid; idx < 135; idx += NTH) {
        int v = idx / 15, f = idx - v * 15;
        float acc = b7[f];
        const float* wr = &w7[f * 60];
        const float* tv = &sT1[v * 60];
        #pragma unroll
        for (int k = 0; k < 60; ++k) acc = fmaf(tv[k], wr[k], acc);
        sTF[idx] = fast_tanh(acc);
    }
    __syncthreads();
    if (tid == 0) {  // RevIN stats over the 135 values (permutation-invariant)
        float sum = 0.f;
        for (int i = 0; i < 135; ++i) sum += sTF[i];
        float mu = sum * (1.f / 135.f);
        float sq = 0.f;
        for (int i = 0; i < 135; ++i) { float d = sTF[i] - mu; sq = fmaf(d, d, sq); }
        float sd = sqrtf(sq * (1.f / 134.f));  // ddof=1
        sST[0] = mu;
        sST[1] = 1.f / fmaxf(sd, 1e-5f);
    }
    __syncthreads();
    const size_t encbase = (size_t)Bn * 288;
    for (int j = tid; j < 135; j += NTH) {
        int q = j / 15, p = j - q * 15;
        float val = (sTF[p * 9 + q] - sST[0]) * sST[1] * rev_w[j] + rev_b[j];
        out[encbase + (size_t)b * 135 + j] = val;
    }
    for (int r = tid; r < 288; r += NTH)
        out[(size_t)b * 288 + r] = sH[r];
}

extern "C" void kernel_launch(void* const* d_in, const int* in_sizes, int n_in,
                              void* d_out, int out_size, void* d_ws, size_t ws_size,
                              hipStream_t stream) {
    const float* x    = (const float*)d_in[0];
    const float* bn_g = (const float*)d_in[1];
    const float* bn_b = (const float*)d_in[2];
    const float* bn_m = (const float*)d_in[3];
    const float* bn_v = (const float*)d_in[4];
    const float* wq2  = (const float*)d_in[5];
    const float* wk2  = (const float*)d_in[6];
    const float* wv2  = (const float*)d_in[7];
    const float* wo2  = (const float*)d_in[8];
    const float* bo2  = (const float*)d_in[9];
    const float* ln2g = (const float*)d_in[10];
    const float* ln2b = (const float*)d_in[11];
    const float* wq4  = (const float*)d_in[12];
    const float* wk4  = (const float*)d_in[13];
    const float* wv4  = (const float*)d_in[14];
    const float* wo4  = (const float*)d_in[15];
    const float* bo4  = (const float*)d_in[16];
    const float* ln4g = (const float*)d_in[17];
    const float* ln4b = (const float*)d_in[18];
    const float* w_ih = (const float*)d_in[19];
    const float* w_hh = (const float*)d_in[20];
    const float* b_ih = (const float*)d_in[21];
    const float* b_hh = (const float*)d_in[22];
    const float* cg_w = (const float*)d_in[23];
    const float* cg_uw= (const float*)d_in[24];
    const float* cg_ub= (const float*)d_in[25];
    const float* w6   = (const float*)d_in[26];
    const float* b6   = (const float*)d_in[27];
    const float* w7   = (const float*)d_in[28];
    const float* b7   = (const float*)d_in[29];
    const float* rev_w= (const float*)d_in[30];
    const float* rev_b= (const float*)d_in[31];

    int Bn = in_sizes[0] / 1080;
    dim3 grid(Bn), block(NTH);
    hipLaunchKernelGGL(se_kernel, grid, block, 0, stream,
                       x, bn_g, bn_b, bn_m, bn_v, wq2, wk2, wv2, wo2, bo2, ln2g, ln2b,
                       wq4, wk4, wv4, wo4, bo4, ln4g, ln4b,
                       w_ih, w_hh, b_ih, b_hh, cg_w, cg_uw, cg_ub,
                       w6, b6, w7, b7, rev_w, rev_b,
                       (float*)d_out, Bn);
}

// Round 2
// 3993.309 us; speedup vs baseline: 1.8777x; 1.8777x over previous
//
#include <hip/hip_runtime.h>
#include <math.h>

#define NTH 256
#define SB 4   // samples per block

__device__ __forceinline__ float fast_sigmoid(float x) { return 1.0f / (1.0f + __expf(-x)); }
__device__ __forceinline__ float fast_tanh(float x)    { return 1.0f - 2.0f / (__expf(2.0f * x) + 1.0f); }

// LDS (floats):
//  0     B0(1080) | 1080 B1 | 2160 B2 | 3240 B3      per-sample scratch (reused)
//  4320  sU[36][120]   LSTM inputs, all 4 samples
//  8640  sH[36][32]    hidden states (wave-private regions)
//  9792  wq2/wk2/wv2/wo2 (81 ea) | 10116 bo2,ln2g,ln2b (9 ea)
//  10143 kv(81) ks(9) qk(9) mu9(9) rs9(9) | 10260 sST(8)
//  10268 bo4(120) ln4g(120) ln4b(120)   -> total 10628 floats = 42.5 KB
// Phase D aliases: sT1 = sm[0..2160), sTF = sm[3240..3780)

extern "C" __global__ void __launch_bounds__(NTH)
se_kernel(const float* __restrict__ x,
          const float* __restrict__ bn_g, const float* __restrict__ bn_b,
          const float* __restrict__ bn_m, const float* __restrict__ bn_v,
          const float* __restrict__ wq2, const float* __restrict__ wk2,
          const float* __restrict__ wv2, const float* __restrict__ wo2,
          const float* __restrict__ bo2, const float* __restrict__ ln2g,
          const float* __restrict__ ln2b,
          const float* __restrict__ wq4, const float* __restrict__ wk4,
          const float* __restrict__ wv4, const float* __restrict__ wo4,
          const float* __restrict__ bo4, const float* __restrict__ ln4g,
          const float* __restrict__ ln4b,
          const float* __restrict__ w_ih, const float* __restrict__ w_hh,
          const float* __restrict__ b_ih, const float* __restrict__ b_hh,
          const float* __restrict__ cg_w, const float* __restrict__ cg_uw,
          const float* __restrict__ cg_ub,
          const float* __restrict__ w6, const float* __restrict__ b6,
          const float* __restrict__ w7, const float* __restrict__ b7,
          const float* __restrict__ rev_w, const float* __restrict__ rev_b,
          float* __restrict__ out, int Bn)
{
    __shared__ __align__(16) float sm[10628];
    const int tid  = threadIdx.x;
    const int lane = tid & 63;
    const int wv   = tid >> 6;
    const int b0   = blockIdx.x * SB;
    const int nsamp = min(SB, Bn - b0);

    float* B0 = sm;
    float* B1 = sm + 1080;
    float* B2 = sm + 2160;
    float* B3 = sm + 3240;
    float* sU = sm + 4320;
    float* sH = sm + 8640;
    float* sWQ2 = sm + 9792; float* sWK2 = sm + 9873;
    float* sWV2 = sm + 9954; float* sWO2 = sm + 10035;
    float* sBO2 = sm + 10116; float* sLN2G = sm + 10125; float* sLN2B = sm + 10134;
    float* sKV = sm + 10143; float* sKS = sm + 10224; float* sQK = sm + 10233;
    float* sMU9 = sm + 10242; float* sRS9 = sm + 10251;
    float* sST  = sm + 10260;
    float* sBO4 = sm + 10268; float* sLN4G = sm + 10388; float* sLN4B = sm + 10508;
    float* sT1 = sm;          // 2160 (aliases B0,B1)
    float* sTF = sm + 3240;   // 540  (aliases B3)

    // ---- Phase 0: stage small shared weights ----
    for (int i = tid; i < 81; i += NTH) {
        sWQ2[i] = wq2[i]; sWK2[i] = wk2[i]; sWV2[i] = wv2[i]; sWO2[i] = wo2[i];
    }
    if (tid < 9) { sBO2[tid] = bo2[tid]; sLN2G[tid] = ln2g[tid]; sLN2B[tid] = ln2b[tid]; }
    for (int i = tid; i < 120; i += NTH) { sBO4[i] = bo4[i]; sLN4G[i] = ln4g[i]; sLN4B[i] = ln4b[i]; }
    __syncthreads();

    // ---- Phases A+B, serial over the block's samples ----
    for (int ss = 0; ss < SB; ++ss) {
        if (ss < nsamp) {
            const int b = b0 + ss;
            // BatchNorm
            for (int i = tid; i < 1080; i += NTH) {
                float xv = x[(size_t)b * 1080 + i];
                B0[i] = (xv - bn_m[i]) * rsqrtf(bn_v[i] + 1e-5f) * bn_g[i] + bn_b[i];
            }
            __syncthreads();
            // A1: Q,K,V (phi = elu+1)
            for (int idx = tid; idx < 1080; idx += NTH) {
                int s = idx / 9, e = idx - s * 9;
                float aq = 0.f, ak = 0.f, av = 0.f;
                #pragma unroll
                for (int d = 0; d < 9; ++d) {
                    float xv = B0[s * 9 + d];
                    aq = fmaf(xv, sWQ2[e * 9 + d], aq);
                    ak = fmaf(xv, sWK2[e * 9 + d], ak);
                    av = fmaf(xv, sWV2[e * 9 + d], av);
                }
                B1[idx] = aq >= 0.f ? aq + 1.f : __expf(aq);
                B2[idx] = ak >= 0.f ? ak + 1.f : __expf(ak);
                B3[idx] = av;
            }
            __syncthreads();
            // A2: kv, ksum
            if (tid < 81) {
                int d = tid / 9, e = tid - d * 9;
                float acc = 0.f;
                for (int s = 0; s < 120; ++s) acc = fmaf(B2[s * 9 + d], B3[s * 9 + e], acc);
                sKV[tid] = acc;
            } else if (tid < 90) {
                int d = tid - 81;
                float acc = 0.f;
                for (int s = 0; s < 120; ++s) acc += B2[s * 9 + d];
                sKS[d] = acc;
            }
            __syncthreads();
            // A3: o
            for (int idx = tid; idx < 1080; idx += NTH) {
                int s = idx / 9, e = idx - s * 9;
                float num = 0.f, den = 0.f;
                #pragma unroll
                for (int d = 0; d < 9; ++d) {
                    float qv = B1[s * 9 + d];
                    num = fmaf(qv, sKV[d * 9 + e], num);
                    den = fmaf(qv, sKS[d], den);
                }
                B0[idx] = num / fmaxf(den, 1e-6f);
            }
            __syncthreads();
            // A4: out_proj + residual
            for (int idx = tid; idx < 1080; idx += NTH) {
                int s = idx / 9, f = idx - s * 9;
                float acc = sBO2[f] + B0[s * 9 + f];
                #pragma unroll
                for (int e = 0; e < 9; ++e) acc = fmaf(B0[s * 9 + e], sWO2[f * 9 + e], acc);
                B1[idx] = acc;
            }
            __syncthreads();
            // A5: LN(9) + transpose -> B2[v][t]
            if (tid < 120) {
                int s = tid;
                float sum = 0.f, sq = 0.f;
                #pragma unroll
                for (int f = 0; f < 9; ++f) { float v = B1[s * 9 + f]; sum += v; sq = fmaf(v, v, sq); }
                float mu = sum * (1.f / 9.f);
                float rs = rsqrtf(sq * (1.f / 9.f) - mu * mu + 1e-5f);
                #pragma unroll
                for (int f = 0; f < 9; ++f)
                    B2[f * 120 + s] = (B1[s * 9 + f] - mu) * rs * sLN2G[f] + sLN2B[f];
            }
            __syncthreads();
            // B1: q4->B0, k4->B1, v4->B3 (thread-per-weight-row)
            for (int idx = tid; idx < 360; idx += NTH) {
                int m = idx / 120, e = idx - m * 120;
                const float* W = (m == 0) ? wq4 : (m == 1) ? wk4 : wv4;
                const float* wr = &W[e * 120];
                float acc[9];
                #pragma unroll
                for (int v = 0; v < 9; ++v) acc[v] = 0.f;
                for (int d = 0; d < 120; ++d) {
                    float wvv = wr[d];
                    #pragma unroll
                    for (int v = 0; v < 9; ++v) acc[v] = fmaf(B2[v * 120 + d], wvv, acc[v]);
                }
                if (m == 2) {
                    #pragma unroll
                    for (int v = 0; v < 9; ++v) B3[v * 120 + e] = acc[v];
                } else {
                    float* dst = (m == 0) ? B0 : B1;
                    #pragma unroll
                    for (int v = 0; v < 9; ++v) {
                        float a = acc[v];
                        dst[v * 120 + e] = a >= 0.f ? a + 1.f : __expf(a);
                    }
                }
            }
            __syncthreads();
            // B2: qk
            if (tid < 9) {
                float acc = 0.f;
                for (int e = 0; e < 120; ++e) acc = fmaf(B0[tid * 120 + e], B1[tid * 120 + e], acc);
                sQK[tid] = acc;
            }
            __syncthreads();
            // B3: o4 -> B0
            for (int idx = tid; idx < 1080; idx += NTH) {
                int v = idx / 120;
                float qk = sQK[v];
                B0[idx] = B3[idx] * (qk / fmaxf(qk, 1e-6f));
            }
            __syncthreads();
            // B4: out_proj + residual -> B1
            if (tid < 120) {
                int e = tid;
                const float* wr = &wo4[e * 120];
                float acc[9];
                #pragma unroll
                for (int v = 0; v < 9; ++v) acc[v] = 0.f;
                for (int f = 0; f < 120; ++f) {
                    float wvv = wr[f];
                    #pragma unroll
                    for (int v = 0; v < 9; ++v) acc[v] = fmaf(B0[v * 120 + f], wvv, acc[v]);
                }
                #pragma unroll
                for (int v = 0; v < 9; ++v)
                    B1[v * 120 + e] = acc[v] + sBO4[e] + B0[v * 120 + e];
            }
            __syncthreads();
            // B5a: LN(120) stats per variable
            if (tid < 9) {
                float sum = 0.f, sq = 0.f;
                for (int e = 0; e < 120; ++e) { float v = B1[tid * 120 + e]; sum += v; sq = fmaf(v, v, sq); }
                float mu = sum * (1.f / 120.f);
                sMU9[tid] = mu;
                sRS9[tid] = rsqrtf(sq * (1.f / 120.f) - mu * mu + 1e-5f);
            }
            __syncthreads();
            // B5b: normalized LSTM input -> sU[(ss*9+v)][t]
            for (int idx = tid; idx < 1080; idx += NTH) {
                int v = idx / 120, e = idx - v * 120;
                sU[(ss * 9 + v) * 120 + e] = (B1[idx] - sMU9[v]) * sRS9[v] * sLN4G[e] + sLN4B[e];
            }
        }
        __syncthreads();
    }

    // ---- Phase C: CGLSTM — weights in registers, h broadcast from LDS ----
    // lane l holds w_hh row l (i rows 0..31 / f rows 32..63) in w0,
    // and (l<32 ? w_hh row 64+l (g rows) : cg_uw row l-32) in w1.
    float4 w0[8], w1[8];
    {
        const float4* wa = (const float4*)&w_hh[lane * 32];
        const float4* wb = (lane < 32) ? (const float4*)&w_hh[(64 + lane) * 32]
                                       : (const float4*)&cg_uw[(lane - 32) * 32];
        #pragma unroll
        for (int q = 0; q < 8; ++q) { w0[q] = wa[q]; w1[q] = wb[q]; }
    }
    float wih_a = w_ih[lane];
    float bias_a = b_ih[lane] + b_hh[lane];
    float wih_b, bias_b;
    if (lane < 32) { wih_b = w_ih[64 + lane]; bias_b = b_ih[64 + lane] + b_hh[64 + lane]; }
    else           { wih_b = cg_w[lane - 32]; bias_b = cg_ub[lane - 32]; }

    // zero this wave's h region (wave-private; in-wave DS ordering suffices)
    #pragma unroll
    for (int j = 0; j < 5; ++j) {
        int idx = lane + 64 * j;
        if (idx < 288) sH[wv * 288 + idx] = 0.f;
    }
    float c[9];
    #pragma unroll
    for (int j = 0; j < 9; ++j) c[j] = 0.f;

    const float* myU = &sU[wv * 9 * 120];
    float* myH = &sH[wv * 288];

    for (int t = 0; t < 120; ++t) {
        #pragma unroll
        for (int j = 0; j < 9; ++j) {
            const float4* h4 = (const float4*)&myH[j * 32];   // wave-uniform -> broadcast
            float xv = myU[j * 120 + t];                      // wave-uniform -> broadcast
            float a  = fmaf(wih_a, xv, bias_a);
            float bc = fmaf(wih_b, xv, bias_b);
            #pragma unroll
            for (int q = 0; q < 8; ++q) {
                float4 h = h4[q];
                a  = fmaf(w0[q].x, h.x, a);   bc = fmaf(w1[q].x, h.x, bc);
                a  = fmaf(w0[q].y, h.y, a);   bc = fmaf(w1[q].y, h.y, bc);
                a  = fmaf(w0[q].z, h.z, a);   bc = fmaf(w1[q].z, h.z, bc);
                a  = fmaf(w0[q].w, h.w, a);   bc = fmaf(w1[q].w, h.w, bc);
            }
            // lane<32: a=i-gate, bc=g-gate(tanh); lane>=32: a=f-gate, bc=contextual gate(sig)
            float sa = 1.f / (1.f + __expf(-a));
            float eb = __expf(lane < 32 ? -2.f * bc : -bc);
            float rb = 1.f / (1.f + eb);
            float sb = lane < 32 ? fmaf(2.f, rb, -1.f) : rb;
            float fg = __shfl(sa, lane | 32);
            float cg = __shfl(sb, lane | 32);
            float cn = fmaf(fg, c[j], sa * sb);
            c[j] = cn;
            float hn = cg * (1.f - 2.f / (__expf(2.f * cn) + 1.f));
            if (lane < 32) myH[j * 32 + lane] = hn;
        }
    }
    __syncthreads();

    // ---- Phase D: conv6(softplus) -> conv7(tanh) -> RevIN, all samples ----
    for (int idx = tid; idx < SB * 540; idx += NTH) {
        int ssd = idx / 540, rem = idx - ssd * 540;
        int v = rem / 60, j = rem - v * 60;
        if (ssd < nsamp) {
            float acc = b6[j];
            const float4* wr = (const float4*)&w6[j * 32];
            const float4* hv = (const float4*)&sH[(ssd * 9 + v) * 32];
            #pragma unroll
            for (int q = 0; q < 8; ++q) {
                float4 w = wr[q], h = hv[q];
                acc = fmaf(w.x, h.x, acc); acc = fmaf(w.y, h.y, acc);
                acc = fmaf(w.z, h.z, acc); acc = fmaf(w.w, h.w, acc);
            }
            sT1[idx] = acc > 15.f ? acc : log1pf(__expf(acc));
        }
    }
    __syncthreads();
    for (int idx = tid; idx < SB * 135; idx += NTH) {
        int ssd = idx / 135, rem = idx - ssd * 135;
        int v = rem / 15, f = rem - v * 15;
        if (ssd < nsamp) {
            float acc = b7[f];
            const float* wr = &w7[f * 60];
            const float* tv = &sT1[ssd * 540 + v * 60];
            #pragma unroll
            for (int k = 0; k < 60; ++k) acc = fmaf(tv[k], wr[k], acc);
            sTF[idx] = fast_tanh(acc);
        }
    }
    __syncthreads();
    if (tid < SB && tid < nsamp) {
        const float* tf = &sTF[tid * 135];
        float sum = 0.f;
        for (int i = 0; i < 135; ++i) sum += tf[i];
        float mu = sum * (1.f / 135.f);
        float sq = 0.f;
        for (int i = 0; i < 135; ++i) { float d = tf[i] - mu; sq = fmaf(d, d, sq); }
        float sd = sqrtf(sq * (1.f / 134.f));  // ddof=1
        sST[tid * 2]     = mu;
        sST[tid * 2 + 1] = 1.f / fmaxf(sd, 1e-5f);
    }
    __syncthreads();
    const size_t encbase = (size_t)Bn * 288;
    for (int idx = tid; idx < SB * 135; idx += NTH) {
        int ssd = idx / 135, j = idx - ssd * 135;
        if (ssd < nsamp) {
            int q = j / 15, p = j - q * 15;
            float val = (sTF[ssd * 135 + p * 9 + q] - sST[ssd * 2]) * sST[ssd * 2 + 1] * rev_w[j] + rev_b[j];
            out[encbase + (size_t)(b0 + ssd) * 135 + j] = val;
        }
    }
    for (int idx = tid; idx < SB * 288; idx += NTH) {
        int ssd = idx / 288, r = idx - ssd * 288;
        if (ssd < nsamp)
            out[(size_t)(b0 + ssd) * 288 + r] = sH[ssd * 288 + r];
    }
}

extern "C" void kernel_launch(void* const* d_in, const int* in_sizes, int n_in,
                              void* d_out, int out_size, void* d_ws, size_t ws_size,
                              hipStream_t stream) {
    const float* x    = (const float*)d_in[0];
    const float* bn_g = (const float*)d_in[1];
    const float* bn_b = (const float*)d_in[2];
    const float* bn_m = (const float*)d_in[3];
    const float* bn_v = (const float*)d_in[4];
    const float* wq2  = (const float*)d_in[5];
    const float* wk2  = (const float*)d_in[6];
    const float* wv2  = (const float*)d_in[7];
    const float* wo2  = (const float*)d_in[8];
    const float* bo2  = (const float*)d_in[9];
    const float* ln2g = (const float*)d_in[10];
    const float* ln2b = (const float*)d_in[11];
    const float* wq4  = (const float*)d_in[12];
    const float* wk4  = (const float*)d_in[13];
    const float* wv4  = (const float*)d_in[14];
    const float* wo4  = (const float*)d_in[15];
    const float* bo4  = (const float*)d_in[16];
    const float* ln4g = (const float*)d_in[17];
    const float* ln4b = (const float*)d_in[18];
    const float* w_ih = (const float*)d_in[19];
    const float* w_hh = (const float*)d_in[20];
    const float* b_ih = (const float*)d_in[21];
    const float* b_hh = (const float*)d_in[22];
    const float* cg_w = (const float*)d_in[23];
    const float* cg_uw= (const float*)d_in[24];
    const float* cg_ub= (const float*)d_in[25];
    const float* w6   = (const float*)d_in[26];
    const float* b6   = (const float*)d_in[27];
    const float* w7   = (const float*)d_in[28];
    const float* b7   = (const float*)d_in[29];
    const float* rev_w= (const float*)d_in[30];
    const float* rev_b= (const float*)d_in[31];

    int Bn = in_sizes[0] / 1080;
    int grid = (Bn + SB - 1) / SB;
    hipLaunchKernelGGL(se_kernel, dim3(grid), dim3(NTH), 0, stream,
                       x, bn_g, bn_b, bn_m, bn_v, wq2, wk2, wv2, wo2, bo2, ln2g, ln2b,
                       wq4, wk4, wv4, wo4, bo4, ln4g, ln4b,
                       w_ih, w_hh, b_ih, b_hh, cg_w, cg_uw, cg_ub,
                       w6, b6, w7, b7, rev_w, rev_b,
                       (float*)d_out, Bn);
}

// Round 3
// 3821.653 us; speedup vs baseline: 1.9621x; 1.0449x over previous
//
#include <hip/hip_runtime.h>
#include <math.h>

#define NTH 256
#define SB 4   // samples per block

__device__ __forceinline__ float fast_sigmoid(float x) { return 1.0f / (1.0f + __expf(-x)); }
__device__ __forceinline__ float fast_tanh(float x)    { return 1.0f - 2.0f / (__expf(2.0f * x) + 1.0f); }

// LDS layout (floats), all section offsets multiple of 4 (16B aligned):
//  sU    @0     (4320)  LSTM inputs / attn intermediates, [36 rows][120]
//  SCR   @4320  (6480)  phase scratch: A uses 4x1080; B pair uses {q,k,v} x2 (3240 per sp)
//  sH    @10800 (1152)  hidden states, [4 waves][288]
//  small weights/stats @11952.. (see pointers below); total 12848 floats = 51.4 KB -> 3 blocks/CU

extern "C" __global__ void __launch_bounds__(NTH, 3)
se_kernel(const float* __restrict__ x,
          const float* __restrict__ bn_g, const float* __restrict__ bn_b,
          const float* __restrict__ bn_m, const float* __restrict__ bn_v,
          const float* __restrict__ wq2, const float* __restrict__ wk2,
          const float* __restrict__ wv2, const float* __restrict__ wo2,
          const float* __restrict__ bo2, const float* __restrict__ ln2g,
          const float* __restrict__ ln2b,
          const float* __restrict__ wq4, const float* __restrict__ wk4,
          const float* __restrict__ wv4, const float* __restrict__ wo4,
          const float* __restrict__ bo4, const float* __restrict__ ln4g,
          const float* __restrict__ ln4b,
          const float* __restrict__ w_ih, const float* __restrict__ w_hh,
          const float* __restrict__ b_ih, const float* __restrict__ b_hh,
          const float* __restrict__ cg_w, const float* __restrict__ cg_uw,
          const float* __restrict__ cg_ub,
          const float* __restrict__ w6, const float* __restrict__ b6,
          const float* __restrict__ w7, const float* __restrict__ b7,
          const float* __restrict__ rev_w, const float* __restrict__ rev_b,
          float* __restrict__ out, int Bn)
{
    __shared__ __align__(16) float sm[12848];
    const int tid  = threadIdx.x;
    const int lane = tid & 63;
    const int wv   = tid >> 6;
    const int b0   = blockIdx.x * SB;
    const int nsamp = min(SB, Bn - b0);

    float* sU  = sm;            // 4320
    float* SCR = sm + 4320;     // 6480
    float* sH  = sm + 10800;    // 1152
    float* sWQ2 = sm + 11952; float* sWK2 = sm + 12036;
    float* sWV2 = sm + 12120; float* sWO2 = sm + 12204;
    float* sBO2 = sm + 12288; float* sLN2G = sm + 12300; float* sLN2B = sm + 12312;
    float* sKV = sm + 12324; float* sKS = sm + 12408;
    float* sQK = sm + 12420; float* sMU = sm + 12440; float* sRS = sm + 12460;
    float* sST = sm + 12480;
    float* sBO4 = sm + 12488; float* sLN4G = sm + 12608; float* sLN4B = sm + 12728;
    float* sT1 = SCR;           // 2160 (Phase D alias)
    float* sTF = SCR + 2160;    // 540  (Phase D alias)

    // ---- Phase 0: stage small shared weights ----
    for (int i = tid; i < 81; i += NTH) {
        sWQ2[i] = wq2[i]; sWK2[i] = wk2[i]; sWV2[i] = wv2[i]; sWO2[i] = wo2[i];
    }
    if (tid < 9) { sBO2[tid] = bo2[tid]; sLN2G[tid] = ln2g[tid]; sLN2B[tid] = ln2b[tid]; }
    for (int i = tid; i < 120; i += NTH) { sBO4[i] = bo4[i]; sLN4G[i] = ln4g[i]; sLN4B[i] = ln4b[i]; }
    __syncthreads();

    // ---- Phase A: lin_attn_2 per sample -> u rows in sU ----
    float* S0 = SCR; float* S1 = SCR + 1080; float* S2 = SCR + 2160; float* S3 = SCR + 3240;
    for (int ss = 0; ss < SB; ++ss) {
        if (ss < nsamp) {
            const int b = b0 + ss;
            // BatchNorm (eval)
            for (int i = tid; i < 1080; i += NTH) {
                float xv = x[(size_t)b * 1080 + i];
                S0[i] = (xv - bn_m[i]) * rsqrtf(bn_v[i] + 1e-5f) * bn_g[i] + bn_b[i];
            }
            __syncthreads();
            // A1: Q,K,V (phi = elu+1)
            for (int idx = tid; idx < 1080; idx += NTH) {
                int s = idx / 9, e = idx - s * 9;
                float aq = 0.f, ak = 0.f, av = 0.f;
                #pragma unroll
                for (int d = 0; d < 9; ++d) {
                    float xv = S0[s * 9 + d];
                    aq = fmaf(xv, sWQ2[e * 9 + d], aq);
                    ak = fmaf(xv, sWK2[e * 9 + d], ak);
                    av = fmaf(xv, sWV2[e * 9 + d], av);
                }
                S1[idx] = aq >= 0.f ? aq + 1.f : __expf(aq);
                S2[idx] = ak >= 0.f ? ak + 1.f : __expf(ak);
                S3[idx] = av;
            }
            __syncthreads();
            // A2: kv[d][e], ksum[d]
            if (tid < 81) {
                int d = tid / 9, e = tid - d * 9;
                float acc = 0.f;
                for (int s = 0; s < 120; ++s) acc = fmaf(S2[s * 9 + d], S3[s * 9 + e], acc);
                sKV[tid] = acc;
            } else if (tid < 90) {
                int d = tid - 81;
                float acc = 0.f;
                for (int s = 0; s < 120; ++s) acc += S2[s * 9 + d];
                sKS[d] = acc;
            }
            __syncthreads();
            // A3: o -> S0
            for (int idx = tid; idx < 1080; idx += NTH) {
                int s = idx / 9, e = idx - s * 9;
                float num = 0.f, den = 0.f;
                #pragma unroll
                for (int d = 0; d < 9; ++d) {
                    float qv = S1[s * 9 + d];
                    num = fmaf(qv, sKV[d * 9 + e], num);
                    den = fmaf(qv, sKS[d], den);
                }
                S0[idx] = num / fmaxf(den, 1e-6f);
            }
            __syncthreads();
            // A4: y = o@wo2^T + bo2 + o -> S1
            for (int idx = tid; idx < 1080; idx += NTH) {
                int s = idx / 9, f = idx - s * 9;
                float acc = sBO2[f] + S0[s * 9 + f];
                #pragma unroll
                for (int e = 0; e < 9; ++e) acc = fmaf(S0[s * 9 + e], sWO2[f * 9 + e], acc);
                S1[idx] = acc;
            }
            __syncthreads();
            // A5: LN(9) + transpose -> sU[ss*9+f][s]
            if (tid < 120) {
                int s = tid;
                float sum = 0.f, sq = 0.f;
                #pragma unroll
                for (int f = 0; f < 9; ++f) { float v = S1[s * 9 + f]; sum += v; sq = fmaf(v, v, sq); }
                float mu = sum * (1.f / 9.f);
                float rs = rsqrtf(sq * (1.f / 9.f) - mu * mu + 1e-5f);
                #pragma unroll
                for (int f = 0; f < 9; ++f)
                    sU[(ss * 9 + f) * 120 + s] = (S1[s * 9 + f] - mu) * rs * sLN2G[f] + sLN2B[f];
            }
        }
        __syncthreads();
    }

    // ---- Phase B: lin_attn_4 per sample pair ----
    for (int p = 0; p < 2; ++p) {
        // B1: q/k/v projections; items (sp, m, e-quad), one per thread
        if (tid < 180) {
            int sp = tid / 90, r2 = tid - sp * 90;
            int m = r2 / 30, eq = r2 - m * 30, e0 = eq * 4;
            const float* W = (m == 0) ? wq4 : (m == 1) ? wk4 : wv4;
            const float* uB = sU + (p * 2 + sp) * 1080;
            float acc[4][9];
            #pragma unroll
            for (int r = 0; r < 4; ++r)
                #pragma unroll
                for (int v = 0; v < 9; ++v) acc[r][v] = 0.f;
            for (int dq = 0; dq < 30; ++dq) {
                float4 u[9];
                #pragma unroll
                for (int v = 0; v < 9; ++v) u[v] = *(const float4*)&uB[v * 120 + dq * 4];
                #pragma unroll
                for (int r = 0; r < 4; ++r) {
                    float4 w = *(const float4*)&W[(e0 + r) * 120 + dq * 4];
                    #pragma unroll
                    for (int v = 0; v < 9; ++v) {
                        acc[r][v] = fmaf(w.x, u[v].x, acc[r][v]);
                        acc[r][v] = fmaf(w.y, u[v].y, acc[r][v]);
                        acc[r][v] = fmaf(w.z, u[v].z, acc[r][v]);
                        acc[r][v] = fmaf(w.w, u[v].w, acc[r][v]);
                    }
                }
            }
            float* dst = SCR + sp * 3240 + m * 1080;
            #pragma unroll
            for (int v = 0; v < 9; ++v) {
                float4 o;
                o.x = acc[0][v]; o.y = acc[1][v]; o.z = acc[2][v]; o.w = acc[3][v];
                if (m != 2) {
                    o.x = o.x >= 0.f ? o.x + 1.f : __expf(o.x);
                    o.y = o.y >= 0.f ? o.y + 1.f : __expf(o.y);
                    o.z = o.z >= 0.f ? o.z + 1.f : __expf(o.z);
                    o.w = o.w >= 0.f ? o.w + 1.f : __expf(o.w);
                }
                *(float4*)&dst[v * 120 + e0] = o;
            }
        }
        __syncthreads();
        // B2: qk[sp][v]
        if (tid < 18) {
            int sp = tid / 9, v = tid - sp * 9;
            const float4* q4 = (const float4*)(SCR + sp * 3240 + v * 120);
            const float4* k4 = (const float4*)(SCR + sp * 3240 + 1080 + v * 120);
            float acc = 0.f;
            for (int i = 0; i < 30; ++i) {
                float4 a = q4[i], bb = k4[i];
                acc = fmaf(a.x, bb.x, acc); acc = fmaf(a.y, bb.y, acc);
                acc = fmaf(a.z, bb.z, acc); acc = fmaf(a.w, bb.w, acc);
            }
            sQK[tid] = acc;
        }
        __syncthreads();
        // B3: o4 = v4 * qk/max(qk,1e-6), in place on v-buffer
        for (int idx = tid; idx < 540; idx += NTH) {
            int sp = idx / 270, off = idx - sp * 270;
            int v = off / 30;
            float qk = sQK[sp * 9 + v];
            float s = qk / fmaxf(qk, 1e-6f);
            float4* pv = (float4*)(SCR + sp * 3240 + 2160) + off;
            float4 t = *pv;
            t.x *= s; t.y *= s; t.z *= s; t.w *= s;
            *pv = t;
        }
        __syncthreads();
        // B4: y = o4@wo4^T + bo4 + o4 -> Y (overwrites q buffer)
        if (tid < 120) {
            int sp = tid / 60, ep = tid - sp * 60;
            int e0 = ep * 2;
            const float* vB = SCR + sp * 3240 + 2160;
            float acc[2][9];
            #pragma unroll
            for (int r = 0; r < 2; ++r)
                #pragma unroll
                for (int v = 0; v < 9; ++v) acc[r][v] = 0.f;
            const float* w0p = &wo4[e0 * 120];
            const float* w1p = &wo4[(e0 + 1) * 120];
            for (int dq = 0; dq < 30; ++dq) {
                float4 wA = *(const float4*)&w0p[dq * 4];
                float4 wB = *(const float4*)&w1p[dq * 4];
                #pragma unroll
                for (int v = 0; v < 9; ++v) {
                    float4 u = *(const float4*)&vB[v * 120 + dq * 4];
                    acc[0][v] = fmaf(wA.x, u.x, acc[0][v]); acc[0][v] = fmaf(wA.y, u.y, acc[0][v]);
                    acc[0][v] = fmaf(wA.z, u.z, acc[0][v]); acc[0][v] = fmaf(wA.w, u.w, acc[0][v]);
                    acc[1][v] = fmaf(wB.x, u.x, acc[1][v]); acc[1][v] = fmaf(wB.y, u.y, acc[1][v]);
                    acc[1][v] = fmaf(wB.z, u.z, acc[1][v]); acc[1][v] = fmaf(wB.w, u.w, acc[1][v]);
                }
            }
            float* Y = SCR + sp * 3240;
            #pragma unroll
            for (int v = 0; v < 9; ++v) {
                float o0 = vB[v * 120 + e0], o1 = vB[v * 120 + e0 + 1];
                Y[v * 120 + e0]     = acc[0][v] + sBO4[e0]     + o0;
                Y[v * 120 + e0 + 1] = acc[1][v] + sBO4[e0 + 1] + o1;
            }
        }
        __syncthreads();
        // B5a: LN(120) stats
        if (tid < 18) {
            int sp = tid / 9, v = tid - sp * 9;
            const float* Y = SCR + sp * 3240 + v * 120;
            float sum = 0.f, sq = 0.f;
            for (int e = 0; e < 120; ++e) { float t = Y[e]; sum += t; sq = fmaf(t, t, sq); }
            float mu = sum * (1.f / 120.f);
            sMU[tid] = mu;
            sRS[tid] = rsqrtf(sq * (1.f / 120.f) - mu * mu + 1e-5f);
        }
        __syncthreads();
        // B5b: normalized LSTM input -> sU (overwrites dead u)
        for (int idx = tid; idx < 540; idx += NTH) {
            int sp = idx / 270, off = idx - sp * 270;
            int v = off / 30, qq = off - v * 30;
            const float* Y = SCR + sp * 3240;
            float4 y = *(const float4*)&Y[v * 120 + qq * 4];
            float4 g = *(const float4*)&sLN4G[qq * 4];
            float4 bb = *(const float4*)&sLN4B[qq * 4];
            float mu = sMU[sp * 9 + v], rs = sRS[sp * 9 + v];
            float4 o;
            o.x = (y.x - mu) * rs * g.x + bb.x;
            o.y = (y.y - mu) * rs * g.y + bb.y;
            o.z = (y.z - mu) * rs * g.z + bb.z;
            o.w = (y.w - mu) * rs * g.w + bb.w;
            *(float4*)&sU[((p * 2 + sp) * 9 + v) * 120 + qq * 4] = o;
        }
        __syncthreads();
    }

    // ---- Phase C: CGLSTM — weights in registers, h broadcast from LDS ----
    float4 w0[8], w1[8];
    {
        const float4* wa = (const float4*)&w_hh[lane * 32];
        const float4* wb = (lane < 32) ? (const float4*)&w_hh[(64 + lane) * 32]
                                       : (const float4*)&cg_uw[(lane - 32) * 32];
        #pragma unroll
        for (int q = 0; q < 8; ++q) { w0[q] = wa[q]; w1[q] = wb[q]; }
    }
    float wih_a  = w_ih[lane];
    float bias_a = b_ih[lane] + b_hh[lane];
    float wih_b  = (lane < 32) ? w_ih[64 + lane] : cg_w[lane - 32];
    float bias_b = (lane < 32) ? (b_ih[64 + lane] + b_hh[64 + lane]) : cg_ub[lane - 32];
    const float sc   = (lane < 32) ? -2.f : -1.f;   // tanh vs sigmoid for the b-activation
    const float mulc = (lane < 32) ?  2.f :  1.f;
    const float addc = (lane < 32) ? -1.f :  0.f;

    #pragma unroll
    for (int j = 0; j < 5; ++j) {
        int idx = lane + 64 * j;
        if (idx < 288) sH[wv * 288 + idx] = 0.f;
    }
    float c[9];
    #pragma unroll
    for (int j = 0; j < 9; ++j) c[j] = 0.f;

    const float* myU = &sU[wv * 1080];
    float* myH = &sH[wv * 288];

    for (int t = 0; t < 120; ++t) {
        #pragma unroll
        for (int j = 0; j < 9; ++j) {
            const float4* h4 = (const float4*)&myH[j * 32];   // wave-uniform -> broadcast
            float xv = myU[j * 120 + t];                      // wave-uniform -> broadcast
            float a  = fmaf(wih_a, xv, bias_a);
            float bc = fmaf(wih_b, xv, bias_b);
            #pragma unroll
            for (int q = 0; q < 8; ++q) {
                float4 h = h4[q];
                a  = fmaf(w0[q].x, h.x, a);   bc = fmaf(w1[q].x, h.x, bc);
                a  = fmaf(w0[q].y, h.y, a);   bc = fmaf(w1[q].y, h.y, bc);
                a  = fmaf(w0[q].z, h.z, a);   bc = fmaf(w1[q].z, h.z, bc);
                a  = fmaf(w0[q].w, h.w, a);   bc = fmaf(w1[q].w, h.w, bc);
            }
            // lane<32: a=i, bc=g(tanh); lane>=32: a=f, bc=contextual gate(sigmoid)
            float sa = 1.f / (1.f + __expf(-a));
            float rb = 1.f / (1.f + __expf(sc * bc));
            float sb = fmaf(mulc, rb, addc);
            float fg = __shfl(sa, lane | 32);
            float cg = __shfl(sb, lane | 32);
            float cn = fmaf(fg, c[j], sa * sb);
            c[j] = cn;
            float hn = cg * (1.f - 2.f / (__expf(2.f * cn) + 1.f));
            if (lane < 32) myH[j * 32 + lane] = hn;
        }
    }
    __syncthreads();

    // ---- Phase D: conv6(softplus) -> conv7(tanh) -> RevIN ----
    for (int idx = tid; idx < SB * 540; idx += NTH) {
        int ssd = idx / 540, rem = idx - ssd * 540;
        int v = rem / 60, j = rem - v * 60;
        if (ssd < nsamp) {
            float acc = b6[j];
            const float4* wr = (const float4*)&w6[j * 32];
            const float4* hv = (const float4*)&sH[ssd * 288 + v * 32];
            #pragma unroll
            for (int q = 0; q < 8; ++q) {
                float4 w = wr[q], h = hv[q];
                acc = fmaf(w.x, h.x, acc); acc = fmaf(w.y, h.y, acc);
                acc = fmaf(w.z, h.z, acc); acc = fmaf(w.w, h.w, acc);
            }
            sT1[idx] = acc > 15.f ? acc : log1pf(__expf(acc));
        }
    }
    __syncthreads();
    for (int idx = tid; idx < SB * 135; idx += NTH) {
        int ssd = idx / 135, rem = idx - ssd * 135;
        int v = rem / 15, f = rem - v * 15;
        if (ssd < nsamp) {
            float acc = b7[f];
            const float4* wr = (const float4*)&w7[f * 60];
            const float4* tv = (const float4*)&sT1[ssd * 540 + v * 60];
            #pragma unroll
            for (int q = 0; q < 15; ++q) {
                float4 w = wr[q], h = tv[q];
                acc = fmaf(w.x, h.x, acc); acc = fmaf(w.y, h.y, acc);
                acc = fmaf(w.z, h.z, acc); acc = fmaf(w.w, h.w, acc);
            }
            sTF[idx] = fast_tanh(acc);
        }
    }
    __syncthreads();
    if (tid < SB && tid < nsamp) {
        const float* tf = &sTF[tid * 135];
        float sum = 0.f;
        for (int i = 0; i < 135; ++i) sum += tf[i];
        float mu = sum * (1.f / 135.f);
        float sq = 0.f;
        for (int i = 0; i < 135; ++i) { float d = tf[i] - mu; sq = fmaf(d, d, sq); }
        float sd = sqrtf(sq * (1.f / 134.f));  // ddof=1
        sST[tid * 2]     = mu;
        sST[tid * 2 + 1] = 1.f / fmaxf(sd, 1e-5f);
    }
    __syncthreads();
    const size_t encbase = (size_t)Bn * 288;
    for (int idx = tid; idx < SB * 135; idx += NTH) {
        int ssd = idx / 135, j = idx - ssd * 135;
        if (ssd < nsamp) {
            int q = j / 15, pp = j - q * 15;
            float val = (sTF[ssd * 135 + pp * 9 + q] - sST[ssd * 2]) * sST[ssd * 2 + 1] * rev_w[j] + rev_b[j];
            out[encbase + (size_t)(b0 + ssd) * 135 + j] = val;
        }
    }
    for (int idx = tid; idx < SB * 288; idx += NTH) {
        int ssd = idx / 288, r = idx - ssd * 288;
        if (ssd < nsamp)
            out[(size_t)(b0 + ssd) * 288 + r] = sH[ssd * 288 + r];
    }
}

extern "C" void kernel_launch(void* const* d_in, const int* in_sizes, int n_in,
                              void* d_out, int out_size, void* d_ws, size_t ws_size,
                              hipStream_t stream) {
    const float* x    = (const float*)d_in[0];
    const float* bn_g = (const float*)d_in[1];
    const float* bn_b = (const float*)d_in[2];
    const float* bn_m = (const float*)d_in[3];
    const float* bn_v = (const float*)d_in[4];
    const float* wq2  = (const float*)d_in[5];
    const float* wk2  = (const float*)d_in[6];
    const float* wv2  = (const float*)d_in[7];
    const float* wo2  = (const float*)d_in[8];
    const float* bo2  = (const float*)d_in[9];
    const float* ln2g = (const float*)d_in[10];
    const float* ln2b = (const float*)d_in[11];
    const float* wq4  = (const float*)d_in[12];
    const float* wk4  = (const float*)d_in[13];
    const float* wv4  = (const float*)d_in[14];
    const float* wo4  = (const float*)d_in[15];
    const float* bo4  = (const float*)d_in[16];
    const float* ln4g = (const float*)d_in[17];
    const float* ln4b = (const float*)d_in[18];
    const float* w_ih = (const float*)d_in[19];
    const float* w_hh = (const float*)d_in[20];
    const float* b_ih = (const float*)d_in[21];
    const float* b_hh = (const float*)d_in[22];
    const float* cg_w = (const float*)d_in[23];
    const float* cg_uw= (const float*)d_in[24];
    const float* cg_ub= (const float*)d_in[25];
    const float* w6   = (const float*)d_in[26];
    const float* b6   = (const float*)d_in[27];
    const float* w7   = (const float*)d_in[28];
    const float* b7   = (const float*)d_in[29];
    const float* rev_w= (const float*)d_in[30];
    const float* rev_b= (const float*)d_in[31];

    int Bn = in_sizes[0] / 1080;
    int grid = (Bn + SB - 1) / SB;
    hipLaunchKernelGGL(se_kernel, dim3(grid), dim3(NTH), 0, stream,
                       x, bn_g, bn_b, bn_m, bn_v, wq2, wk2, wv2, wo2, bo2, ln2g, ln2b,
                       wq4, wk4, wv4, wo4, bo4, ln4g, ln4b,
                       w_ih, w_hh, b_ih, b_hh, cg_w, cg_uw, cg_ub,
                       w6, b6, w7, b7, rev_w, rev_b,
                       (float*)d_out, Bn);
}

// Round 7
// 3098.992 us; speedup vs baseline: 2.4196x; 1.2332x over previous
//
#include <hip/hip_runtime.h>
#include <math.h>

#define NTH 256
#define SB 4   // samples per block

typedef __attribute__((ext_vector_type(8))) short bf16x8;
typedef __attribute__((ext_vector_type(4))) float f32x4;

__device__ __forceinline__ float fast_sigmoid(float x) { return 1.0f / (1.0f + __expf(-x)); }
__device__ __forceinline__ float fast_tanh(float x)    { return 1.0f - 2.0f / (__expf(2.0f * x) + 1.0f); }
__device__ __forceinline__ short f2bf(float x) {
    unsigned u = __float_as_uint(x);
    return (short)((u + 0x7FFFu + ((u >> 16) & 1u)) >> 16);   // RNE
}

// LDS layout (dwords):
//  sU   @0      (4320)  [36 rows][120]  attn outputs -> LSTM inputs
//  SCR  @4320   (6480)  A: 4x1080 | B(pair): 2x3240 | D: sT1(2160)+sTF(540)
//  sHf  @8688   (2112)  fp32 h, 48 rows x 44 (aliases SCR top; dead during C/D's sT1 use)
//  weights/stats @10800..11696  -> 11696 dwords = 46.8 KB -> 3 blocks/CU

extern "C" __global__ void __launch_bounds__(NTH, 3)
se_kernel(const float* __restrict__ x,
          const float* __restrict__ bn_g, const float* __restrict__ bn_b,
          const float* __restrict__ bn_m, const float* __restrict__ bn_v,
          const float* __restrict__ wq2, const float* __restrict__ wk2,
          const float* __restrict__ wv2, const float* __restrict__ wo2,
          const float* __restrict__ bo2, const float* __restrict__ ln2g,
          const float* __restrict__ ln2b,
          const float* __restrict__ wq4, const float* __restrict__ wk4,
          const float* __restrict__ wv4, const float* __restrict__ wo4,
          const float* __restrict__ bo4, const float* __restrict__ ln4g,
          const float* __restrict__ ln4b,
          const float* __restrict__ w_ih, const float* __restrict__ w_hh,
          const float* __restrict__ b_ih, const float* __restrict__ b_hh,
          const float* __restrict__ cg_w, const float* __restrict__ cg_uw,
          const float* __restrict__ cg_ub,
          const float* __restrict__ w6, const float* __restrict__ b6,
          const float* __restrict__ w7, const float* __restrict__ b7,
          const float* __restrict__ rev_w, const float* __restrict__ rev_b,
          float* __restrict__ out, int Bn)
{
    __shared__ __align__(16) float sm[11696];
    const int tid  = threadIdx.x;
    const int lane = tid & 63;
    const int wv   = tid >> 6;
    const int b0   = blockIdx.x * SB;
    const int nsamp = min(SB, Bn - b0);

    float* sU  = sm;            // 4320
    float* SCR = sm + 4320;     // 6480
    float* sHf = sm + 8688;     // 2112 : 48 rows x 44 (aliases SCR[4368..6480))
    float* sWQ2 = sm + 10800; float* sWK2 = sm + 10884;
    float* sWV2 = sm + 10968; float* sWO2 = sm + 11052;
    float* sBO2 = sm + 11136; float* sLN2G = sm + 11148; float* sLN2B = sm + 11160;
    float* sKV = sm + 11172; float* sKS = sm + 11256;
    float* sQK = sm + 11268; float* sMU = sm + 11288; float* sRS = sm + 11308;
    float* sST = sm + 11328;
    float* sBO4 = sm + 11336; float* sLN4G = sm + 11456; float* sLN4B = sm + 11576;
    float* sT1 = SCR;           // 2160 (Phase D alias)
    float* sTF = SCR + 2160;    // 540  (Phase D alias)

    // ---- Phase 0: stage small shared weights (R3-proven) ----
    for (int i = tid; i < 81; i += NTH) {
        sWQ2[i] = wq2[i]; sWK2[i] = wk2[i]; sWV2[i] = wv2[i]; sWO2[i] = wo2[i];
    }
    if (tid < 9) { sBO2[tid] = bo2[tid]; sLN2G[tid] = ln2g[tid]; sLN2B[tid] = ln2b[tid]; }
    for (int i = tid; i < 120; i += NTH) { sBO4[i] = bo4[i]; sLN4G[i] = ln4g[i]; sLN4B[i] = ln4b[i]; }
    __syncthreads();

    // ---- Phase A: lin_attn_2 per sample -> u rows in sU (R3-proven) ----
    float* S0 = SCR; float* S1 = SCR + 1080; float* S2 = SCR + 2160; float* S3 = SCR + 3240;
    for (int ss = 0; ss < SB; ++ss) {
        if (ss < nsamp) {
            const int b = b0 + ss;
            for (int i = tid; i < 1080; i += NTH) {
                float xv = x[(size_t)b * 1080 + i];
                S0[i] = (xv - bn_m[i]) * rsqrtf(bn_v[i] + 1e-5f) * bn_g[i] + bn_b[i];
            }
            __syncthreads();
            for (int idx = tid; idx < 1080; idx += NTH) {
                int s = idx / 9, e = idx - s * 9;
                float aq = 0.f, ak = 0.f, av = 0.f;
                #pragma unroll
                for (int d = 0; d < 9; ++d) {
                    float xv = S0[s * 9 + d];
                    aq = fmaf(xv, sWQ2[e * 9 + d], aq);
                    ak = fmaf(xv, sWK2[e * 9 + d], ak);
                    av = fmaf(xv, sWV2[e * 9 + d], av);
                }
                S1[idx] = aq >= 0.f ? aq + 1.f : __expf(aq);
                S2[idx] = ak >= 0.f ? ak + 1.f : __expf(ak);
                S3[idx] = av;
            }
            __syncthreads();
            if (tid < 81) {
                int d = tid / 9, e = tid - d * 9;
                float acc = 0.f;
                for (int s = 0; s < 120; ++s) acc = fmaf(S2[s * 9 + d], S3[s * 9 + e], acc);
                sKV[tid] = acc;
            } else if (tid < 90) {
                int d = tid - 81;
                float acc = 0.f;
                for (int s = 0; s < 120; ++s) acc += S2[s * 9 + d];
                sKS[d] = acc;
            }
            __syncthreads();
            for (int idx = tid; idx < 1080; idx += NTH) {
                int s = idx / 9, e = idx - s * 9;
                float num = 0.f, den = 0.f;
                #pragma unroll
                for (int d = 0; d < 9; ++d) {
                    float qv = S1[s * 9 + d];
                    num = fmaf(qv, sKV[d * 9 + e], num);
                    den = fmaf(qv, sKS[d], den);
                }
                S0[idx] = num / fmaxf(den, 1e-6f);
            }
            __syncthreads();
            for (int idx = tid; idx < 1080; idx += NTH) {
                int s = idx / 9, f = idx - s * 9;
                float acc = sBO2[f] + S0[s * 9 + f];
                #pragma unroll
                for (int e = 0; e < 9; ++e) acc = fmaf(S0[s * 9 + e], sWO2[f * 9 + e], acc);
                S1[idx] = acc;
            }
            __syncthreads();
            if (tid < 120) {
                int s = tid;
                float sum = 0.f, sq = 0.f;
                #pragma unroll
                for (int f = 0; f < 9; ++f) { float v = S1[s * 9 + f]; sum += v; sq = fmaf(v, v, sq); }
                float mu = sum * (1.f / 9.f);
                float rs = rsqrtf(sq * (1.f / 9.f) - mu * mu + 1e-5f);
                #pragma unroll
                for (int f = 0; f < 9; ++f)
                    sU[(ss * 9 + f) * 120 + s] = (S1[s * 9 + f] - mu) * rs * sLN2G[f] + sLN2B[f];
            }
        }
        __syncthreads();
    }

    // ---- Phase B: lin_attn_4 per sample PAIR (R3-proven, verbatim) ----
    for (int p = 0; p < 2; ++p) {
        if (tid < 180) {
            int sp = tid / 90, r2 = tid - sp * 90;
            int m = r2 / 30, eq = r2 - m * 30, e0 = eq * 4;
            const float* W = (m == 0) ? wq4 : (m == 1) ? wk4 : wv4;
            const float* uB = sU + (p * 2 + sp) * 1080;
            float acc[4][9];
            #pragma unroll
            for (int r = 0; r < 4; ++r)
                #pragma unroll
                for (int v = 0; v < 9; ++v) acc[r][v] = 0.f;
            for (int dq = 0; dq < 30; ++dq) {
                float4 u[9];
                #pragma unroll
                for (int v = 0; v < 9; ++v) u[v] = *(const float4*)&uB[v * 120 + dq * 4];
                #pragma unroll
                for (int r = 0; r < 4; ++r) {
                    float4 w = *(const float4*)&W[(e0 + r) * 120 + dq * 4];
                    #pragma unroll
                    for (int v = 0; v < 9; ++v) {
                        acc[r][v] = fmaf(w.x, u[v].x, acc[r][v]);
                        acc[r][v] = fmaf(w.y, u[v].y, acc[r][v]);
                        acc[r][v] = fmaf(w.z, u[v].z, acc[r][v]);
                        acc[r][v] = fmaf(w.w, u[v].w, acc[r][v]);
                    }
                }
            }
            float* dst = SCR + sp * 3240 + m * 1080;
            #pragma unroll
            for (int v = 0; v < 9; ++v) {
                float4 o;
                o.x = acc[0][v]; o.y = acc[1][v]; o.z = acc[2][v]; o.w = acc[3][v];
                if (m != 2) {
                    o.x = o.x >= 0.f ? o.x + 1.f : __expf(o.x);
                    o.y = o.y >= 0.f ? o.y + 1.f : __expf(o.y);
                    o.z = o.z >= 0.f ? o.z + 1.f : __expf(o.z);
                    o.w = o.w >= 0.f ? o.w + 1.f : __expf(o.w);
                }
                *(float4*)&dst[v * 120 + e0] = o;
            }
        }
        __syncthreads();
        if (tid < 18) {
            int sp = tid / 9, v = tid - sp * 9;
            const float4* q4 = (const float4*)(SCR + sp * 3240 + v * 120);
            const float4* k4 = (const float4*)(SCR + sp * 3240 + 1080 + v * 120);
            float acc = 0.f;
            for (int i = 0; i < 30; ++i) {
                float4 a = q4[i], bb = k4[i];
                acc = fmaf(a.x, bb.x, acc); acc = fmaf(a.y, bb.y, acc);
                acc = fmaf(a.z, bb.z, acc); acc = fmaf(a.w, bb.w, acc);
            }
            sQK[tid] = acc;
        }
        __syncthreads();
        for (int idx = tid; idx < 540; idx += NTH) {
            int sp = idx / 270, off = idx - sp * 270;
            int v = off / 30;
            float qk = sQK[sp * 9 + v];
            float s = qk / fmaxf(qk, 1e-6f);
            float4* pv = (float4*)(SCR + sp * 3240 + 2160) + off;
            float4 t = *pv;
            t.x *= s; t.y *= s; t.z *= s; t.w *= s;
            *pv = t;
        }
        __syncthreads();
        if (tid < 120) {
            int sp = tid / 60, ep = tid - sp * 60;
            int e0 = ep * 2;
            const float* vB = SCR + sp * 3240 + 2160;
            float acc[2][9];
            #pragma unroll
            for (int r = 0; r < 2; ++r)
                #pragma unroll
                for (int v = 0; v < 9; ++v) acc[r][v] = 0.f;
            const float* w0p = &wo4[e0 * 120];
            const float* w1p = &wo4[(e0 + 1) * 120];
            for (int dq = 0; dq < 30; ++dq) {
                float4 wA = *(const float4*)&w0p[dq * 4];
                float4 wB = *(const float4*)&w1p[dq * 4];
                #pragma unroll
                for (int v = 0; v < 9; ++v) {
                    float4 u = *(const float4*)&vB[v * 120 + dq * 4];
                    acc[0][v] = fmaf(wA.x, u.x, acc[0][v]); acc[0][v] = fmaf(wA.y, u.y, acc[0][v]);
                    acc[0][v] = fmaf(wA.z, u.z, acc[0][v]); acc[0][v] = fmaf(wA.w, u.w, acc[0][v]);
                    acc[1][v] = fmaf(wB.x, u.x, acc[1][v]); acc[1][v] = fmaf(wB.y, u.y, acc[1][v]);
                    acc[1][v] = fmaf(wB.z, u.z, acc[1][v]); acc[1][v] = fmaf(wB.w, u.w, acc[1][v]);
                }
            }
            float* Y = SCR + sp * 3240;
            #pragma unroll
            for (int v = 0; v < 9; ++v) {
                float o0 = vB[v * 120 + e0], o1 = vB[v * 120 + e0 + 1];
                Y[v * 120 + e0]     = acc[0][v] + sBO4[e0]     + o0;
                Y[v * 120 + e0 + 1] = acc[1][v] + sBO4[e0 + 1] + o1;
            }
        }
        __syncthreads();
        if (tid < 18) {
            int sp = tid / 9, v = tid - sp * 9;
            const float* Y = SCR + sp * 3240 + v * 120;
            float sum = 0.f, sq = 0.f;
            for (int e = 0; e < 120; ++e) { float t = Y[e]; sum += t; sq = fmaf(t, t, sq); }
            float mu = sum * (1.f / 120.f);
            sMU[tid] = mu;
            sRS[tid] = rsqrtf(sq * (1.f / 120.f) - mu * mu + 1e-5f);
        }
        __syncthreads();
        for (int idx = tid; idx < 540; idx += NTH) {
            int sp = idx / 270, off = idx - sp * 270;
            int v = off / 30, qq = off - v * 30;
            const float* Y = SCR + sp * 3240;
            float4 y = *(const float4*)&Y[v * 120 + qq * 4];
            float4 g = *(const float4*)&sLN4G[qq * 4];
            float4 bb = *(const float4*)&sLN4B[qq * 4];
            float mu = sMU[sp * 9 + v], rs = sRS[sp * 9 + v];
            float4 o;
            o.x = (y.x - mu) * rs * g.x + bb.x;
            o.y = (y.y - mu) * rs * g.y + bb.y;
            o.z = (y.z - mu) * rs * g.z + bb.z;
            o.w = (y.w - mu) * rs * g.w + bb.w;
            *(float4*)&sU[((p * 2 + sp) * 9 + v) * 120 + qq * 4] = o;
        }
        __syncthreads();
    }

    // ---- Phase C: CGLSTM via MFMA with RUNTIME-PROBED D layout ----
    for (int i = tid; i < 2112; i += NTH) sHf[i] = 0.f;   // h0 = 0
    __syncthreads();

    const int c = lane & 15, q = lane >> 4;
    bf16x8 bfr[8]; float wxv[8], bsv[8];
    int grow[4] = {0, 0, 0, 0}; int pcol = 0;
    if (wv < 3) {
        // Probe 1: A(m,0)=m, B(0,n)=1  -> D slot value = its ROW
        // Probe 2: A(m,0)=1, B(0,n)=n  -> D slot value = its COLUMN
        bf16x8 pa, pb, pa2, pb2;
        #pragma unroll
        for (int j = 0; j < 8; ++j) { pa[j] = 0; pb[j] = 0; pa2[j] = 0; pb2[j] = 0; }
        if (q == 0) {
            pa[0]  = f2bf((float)c); pb[0]  = f2bf(1.0f);
            pa2[0] = f2bf(1.0f);     pb2[0] = f2bf((float)c);
        }
        f32x4 zc; zc[0] = zc[1] = zc[2] = zc[3] = 0.f;
        f32x4 prr = __builtin_amdgcn_mfma_f32_16x16x32_bf16(pa,  pb,  zc, 0, 0, 0);
        f32x4 pcc = __builtin_amdgcn_mfma_f32_16x16x32_bf16(pa2, pb2, zc, 0, 0, 0);
        #pragma unroll
        for (int r = 0; r < 4; ++r) grow[r] = wv * 16 + (int)(prr[r] + 0.5f);
        pcol = (int)(pcc[0] + 0.5f);

        // Loop-invariant B-fragments + rank-1 x/bias constants, per probed column.
        #pragma unroll
        for (int T = 0; T < 8; ++T) {
            int gate = T >> 1, kk = ((T & 1) << 4) + pcol;
            const float* wr; float wx, bs;
            if (gate < 3) {
                int n = gate * 32 + kk;
                wr = &w_hh[n * 32]; wx = w_ih[n]; bs = b_ih[n] + b_hh[n];
            } else {
                wr = &cg_uw[kk * 32]; wx = cg_w[kk]; bs = cg_ub[kk];
            }
            bf16x8 tv;
            #pragma unroll
            for (int j = 0; j < 8; ++j) tv[j] = f2bf(wr[q * 8 + j]);
            bfr[T] = tv; wxv[T] = wx; bsv[T] = bs;
        }
    }
    float cst[8];
    #pragma unroll
    for (int i = 0; i < 8; ++i) cst[i] = 0.f;
    const int live9 = nsamp * 9;
    const float* arowp = &sHf[(wv * 16 + c) * 44 + q * 8];  // lane supplies h-row wv*16+c

    for (int t = 0; t < 120; ++t) {
        float4 hA, hB; float xr[4];
        if (wv < 3) {
            hA = *(const float4*)arowp;
            hB = *(const float4*)(arowp + 4);
            #pragma unroll
            for (int r = 0; r < 4; ++r)
                xr[r] = (grow[r] < live9) ? sU[grow[r] * 120 + t] : 0.f;
        }
        __syncthreads();   // reads of h(t-1) complete before writes of h(t)
        if (wv < 3) {
            bf16x8 af;
            af[0] = f2bf(hA.x); af[1] = f2bf(hA.y); af[2] = f2bf(hA.z); af[3] = f2bf(hA.w);
            af[4] = f2bf(hB.x); af[5] = f2bf(hB.y); af[6] = f2bf(hB.z); af[7] = f2bf(hB.w);
            f32x4 acc[8];
            #pragma unroll
            for (int T = 0; T < 8; ++T) {
                f32x4 ci;
                #pragma unroll
                for (int r = 0; r < 4; ++r) ci[r] = fmaf(wxv[T], xr[r], bsv[T]);
                acc[T] = __builtin_amdgcn_mfma_f32_16x16x32_bf16(af, bfr[T], ci, 0, 0, 0);
            }
            #pragma unroll
            for (int kh = 0; kh < 2; ++kh) {
                #pragma unroll
                for (int r = 0; r < 4; ++r) {
                    float si  = fast_sigmoid(acc[kh][r]);       // i
                    float sf  = fast_sigmoid(acc[2 + kh][r]);   // f
                    float tg  = fast_tanh(acc[4 + kh][r]);      // g
                    float sgc = fast_sigmoid(acc[6 + kh][r]);   // contextual gate (old h)
                    float cn = fmaf(sf, cst[kh * 4 + r], si * tg);
                    cst[kh * 4 + r] = cn;
                    sHf[grow[r] * 44 + (kh << 4) + pcol] = sgc * fast_tanh(cn);
                }
            }
        }
        __syncthreads();   // h(t) visible before next iteration's reads
    }

    // cglstm_out (output 0) straight from the LDS h-plane (layout-independent)
    for (int idx = tid; idx < SB * 288; idx += NTH) {
        int ssd = idx / 288, r = idx - ssd * 288;
        if (ssd < nsamp) {
            int v = r >> 5, k = r & 31;
            out[(size_t)(b0 + ssd) * 288 + r] = sHf[(ssd * 9 + v) * 44 + k];
        }
    }

    // ---- Phase D: conv6(softplus) -> conv7(tanh) -> RevIN ----
    for (int idx = tid; idx < SB * 540; idx += NTH) {
        int ssd = idx / 540, rem = idx - ssd * 540;
        int v = rem / 60, j = rem - v * 60;
        if (ssd < nsamp) {
            float acc = b6[j];
            const float4* wr4 = (const float4*)&w6[j * 32];
            const float4* hv = (const float4*)&sHf[(ssd * 9 + v) * 44];
            #pragma unroll
            for (int qq = 0; qq < 8; ++qq) {
                float4 w = wr4[qq], h = hv[qq];
                acc = fmaf(w.x, h.x, acc); acc = fmaf(w.y, h.y, acc);
                acc = fmaf(w.z, h.z, acc); acc = fmaf(w.w, h.w, acc);
            }
            sT1[idx] = acc > 15.f ? acc : log1pf(__expf(acc));
        }
    }
    __syncthreads();
    for (int idx = tid; idx < SB * 135; idx += NTH) {
        int ssd = idx / 135, rem = idx - ssd * 135;
        int v = rem / 15, f = rem - v * 15;
        if (ssd < nsamp) {
            float acc = b7[f];
            const float4* wr = (const float4*)&w7[f * 60];
            const float4* tv = (const float4*)&sT1[ssd * 540 + v * 60];
            #pragma unroll
            for (int qq = 0; qq < 15; ++qq) {
                float4 w = wr[qq], h = tv[qq];
                acc = fmaf(w.x, h.x, acc); acc = fmaf(w.y, h.y, acc);
                acc = fmaf(w.z, h.z, acc); acc = fmaf(w.w, h.w, acc);
            }
            sTF[idx] = fast_tanh(acc);
        }
    }
    __syncthreads();
    if (tid < SB && tid < nsamp) {
        const float* tf = &sTF[tid * 135];
        float sum = 0.f;
        for (int i = 0; i < 135; ++i) sum += tf[i];
        float mu = sum * (1.f / 135.f);
        float sq = 0.f;
        for (int i = 0; i < 135; ++i) { float d = tf[i] - mu; sq = fmaf(d, d, sq); }
        float sd = sqrtf(sq * (1.f / 134.f));  // ddof=1
        sST[tid * 2]     = mu;
        sST[tid * 2 + 1] = 1.f / fmaxf(sd, 1e-5f);
    }
    __syncthreads();
    const size_t encbase = (size_t)Bn * 288;
    for (int idx = tid; idx < SB * 135; idx += NTH) {
        int ssd = idx / 135, j = idx - ssd * 135;
        if (ssd < nsamp) {
            int qq = j / 15, pp = j - qq * 15;
            float val = (sTF[ssd * 135 + pp * 9 + qq] - sST[ssd * 2]) * sST[ssd * 2 + 1] * rev_w[j] + rev_b[j];
            out[encbase + (size_t)(b0 + ssd) * 135 + j] = val;
        }
    }
}

extern "C" void kernel_launch(void* const* d_in, const int* in_sizes, int n_in,
                              void* d_out, int out_size, void* d_ws, size_t ws_size,
                              hipStream_t stream) {
    const float* x    = (const float*)d_in[0];
    const float* bn_g = (const float*)d_in[1];
    const float* bn_b = (const float*)d_in[2];
    const float* bn_m = (const float*)d_in[3];
    const float* bn_v = (const float*)d_in[4];
    const float* wq2  = (const float*)d_in[5];
    const float* wk2  = (const float*)d_in[6];
    const float* wv2  = (const float*)d_in[7];
    const float* wo2  = (const float*)d_in[8];
    const float* bo2  = (const float*)d_in[9];
    const float* ln2g = (const float*)d_in[10];
    const float* ln2b = (const float*)d_in[11];
    const float* wq4  = (const float*)d_in[12];
    const float* wk4  = (const float*)d_in[13];
    const float* wv4  = (const float*)d_in[14];
    const float* wo4  = (const float*)d_in[15];
    const float* bo4  = (const float*)d_in[16];
    const float* ln4g = (const float*)d_in[17];
    const float* ln4b = (const float*)d_in[18];
    const float* w_ih = (const float*)d_in[19];
    const float* w_hh = (const float*)d_in[20];
    const float* b_ih = (const float*)d_in[21];
    const float* b_hh = (const float*)d_in[22];
    const float* cg_w = (const float*)d_in[23];
    const float* cg_uw= (const float*)d_in[24];
    const float* cg_ub= (const float*)d_in[25];
    const float* w6   = (const float*)d_in[26];
    const float* b6   = (const float*)d_in[27];
    const float* w7   = (const float*)d_in[28];
    const float* b7   = (const float*)d_in[29];
    const float* rev_w= (const float*)d_in[30];
    const float* rev_b= (const float*)d_in[31];

    int Bn = in_sizes[0] / 1080;
    int grid = (Bn + SB - 1) / SB;
    hipLaunchKernelGGL(se_kernel, dim3(grid), dim3(NTH), 0, stream,
                       x, bn_g, bn_b, bn_m, bn_v, wq2, wk2, wv2, wo2, bo2, ln2g, ln2b,
                       wq4, wk4, wv4, wo4, bo4, ln4g, ln4b,
                       w_ih, w_hh, b_ih, b_hh, cg_w, cg_uw, cg_ub,
                       w6, b6, w7, b7, rev_w, rev_b,
                       (float*)d_out, Bn);
}